// Round 8
// baseline (326.046 us; speedup 1.0000x reference)
//
#include <hip/hip_runtime.h>
#include <cstdint>
#include <cstddef>

#define NB 20000
#define NT 1000
#define P_PAIRS 50000
#define MARGIN 2.0f
#define RANK_W 0.3f
#define NEG_SENT -1e9f

#define G2 625           // mega-kernel grid; 625*32 rows = 20000, 625*80 pairs = 50000
#define ROWS_PB 32
#define PAIRS_PB 80

// ---------------- workspace layout (bytes) ----------------
// [0,        2560000)  label bitmask: uint32 [NB][32]
// [2560000]  float sq_total
// [2560004]  float rsum
// [2560008]  uint  nrp
// [2560012]  uint  ticket
// [2560016]  uint  barA
// [2560020]  uint  barB
// (pad to 2560032; zero range = 160002 uint4)
// [2560032, 2960032)  float top5[NB][5]
// [2960032, 3040032)  int   numneg[NB]

#define ZERO_U4 160002

__global__ void zero_ws_kernel(uint4* __restrict__ ws) {
    int i = blockIdx.x * blockDim.x + threadIdx.x;
    if (i < ZERO_U4) ws[i] = make_uint4(0u, 0u, 0u, 0u);
}

// software grid barrier: safe because G2=625 < guaranteed co-resident capacity
// (__launch_bounds__(256,4) -> >=4 blocks/CU -> 1024 blocks)
__device__ __forceinline__ void global_barrier(unsigned int* ctr, unsigned int target) {
    __syncthreads();
    if (threadIdx.x == 0) {
        __threadfence();                 // release: my prior writes visible device-wide
        atomicAdd(ctr, 1u);
        while (__hip_atomic_load(ctr, __ATOMIC_ACQUIRE, __HIP_MEMORY_SCOPE_AGENT) < target) {
            __builtin_amdgcn_s_sleep(8);
        }
    }
    __syncthreads();
    __threadfence();                     // acquire for all threads in block
}

// branchless sorted-desc insert of x into (t0>=t1>=t2>=t3>=t4)
#define INSERT5(x)                                        \
    {                                                     \
        float _x = (x);                                   \
        float n0 = fmaxf(t0, _x), s0 = fminf(t0, _x);     \
        float n1 = fmaxf(t1, s0), s1 = fminf(t1, s0);     \
        float n2 = fmaxf(t2, s1), s2 = fminf(t2, s1);     \
        float n3 = fmaxf(t3, s2), s3 = fminf(t3, s2);     \
        float n4 = fmaxf(t4, s3);                         \
        t0 = n0; t1 = n1; t2 = n2; t3 = n3; t4 = n4;      \
    }

#define PROC1(xv, lab)                                              \
    {                                                               \
        float _x = (xv);                                            \
        int _lab = (lab);                                           \
        float _s = __builtin_amdgcn_rcpf(1.0f + __expf(-_x));       \
        float _d = (float)_lab - _s;                                \
        sq = fmaf(_d, _d, sq);                                      \
        pcount += _lab;                                             \
        float _xx = _lab ? NEG_SENT : _x;                           \
        INSERT5(_xx);                                               \
    }

#define PROC4(v, bits)                        \
    PROC1((v).x, (int)(((bits) >> 0) & 1u));  \
    PROC1((v).y, (int)(((bits) >> 1) & 1u));  \
    PROC1((v).z, (int)(((bits) >> 2) & 1u));  \
    PROC1((v).w, (int)(((bits) >> 3) & 1u));

#define BATCH4(k0)                                                   \
    {                                                                \
        float4 va = rowp[gl + 16 * ((k0) + 0)];                      \
        float4 vb = rowp[gl + 16 * ((k0) + 1)];                      \
        float4 vc = rowp[gl + 16 * ((k0) + 2)];                      \
        float4 vd = rowp[gl + 16 * ((k0) + 3)];                      \
        unsigned int ba = (mrow[wb + 2 * ((k0) + 0)] >> sh) & 0xFu;  \
        unsigned int bbb = (mrow[wb + 2 * ((k0) + 1)] >> sh) & 0xFu; \
        unsigned int bc = (mrow[wb + 2 * ((k0) + 2)] >> sh) & 0xFu;  \
        unsigned int bd = (mrow[wb + 2 * ((k0) + 3)] >> sh) & 0xFu;  \
        PROC4(va, ba); PROC4(vb, bbb); PROC4(vc, bc); PROC4(vd, bd); \
    }

// One persistent kernel: scatter -> barrier -> rows -> barrier -> pairs -> finalize
__global__ __launch_bounds__(256, 4)
void mega_kernel(const float* __restrict__ scores,
                 const int* __restrict__ pb,
                 const int* __restrict__ pt,
                 unsigned int* __restrict__ mask,
                 float* __restrict__ top5,
                 int* __restrict__ numneg,
                 float* __restrict__ sq_total,
                 float* __restrict__ rsum,
                 unsigned int* __restrict__ nrp,
                 unsigned int* __restrict__ ticket,
                 unsigned int* __restrict__ barA,
                 unsigned int* __restrict__ barB,
                 float* __restrict__ out) {
    // ---- Phase S: scatter 80 pairs per block ----
    if (threadIdx.x < PAIRS_PB) {
        int p = blockIdx.x * PAIRS_PB + threadIdx.x;
        int b = pb[p];
        int t = pt[p];
        atomicOr(&mask[b * 32 + (t >> 5)], 1u << (t & 31));
    }
    global_barrier(barA, G2);

    // ---- Phase R: 32 rows per block, 2 rounds of 16 (4 waves x 4 groups) ----
    const int lane = threadIdx.x & 63;
    const int wib  = threadIdx.x >> 6;      // wave in block 0..3
    const int grp  = lane >> 4;             // group in wave  0..3
    const int gl   = lane & 15;             // lane in group  0..15
    const int wb   = gl >> 3;               // mask word base (0/1)
    const int sh   = (gl & 7) * 4;          // nibble shift (constant per lane)

    float block_sq = 0.0f;                  // accumulated on gl==0 lanes

    #pragma unroll
    for (int round = 0; round < 2; ++round) {
        const int row = blockIdx.x * ROWS_PB + round * 16 + (wib * 4 + grp);
        const float4* rowp = reinterpret_cast<const float4*>(scores + (size_t)row * NT);
        const unsigned int* mrow = mask + row * 32;

        float t0 = NEG_SENT, t1 = NEG_SENT, t2 = NEG_SENT, t3 = NEG_SENT, t4 = NEG_SENT;
        float sq = 0.0f;
        int pcount = 0;

        BATCH4(0);
        BATCH4(4);
        BATCH4(8);
        {   // k = 12..14
            float4 va = rowp[gl + 192];
            float4 vb = rowp[gl + 208];
            float4 vc = rowp[gl + 224];
            unsigned int ba = (mrow[wb + 24] >> sh) & 0xFu;
            unsigned int bbb = (mrow[wb + 26] >> sh) & 0xFu;
            unsigned int bc = (mrow[wb + 28] >> sh) & 0xFu;
            PROC4(va, ba); PROC4(vb, bbb); PROC4(vc, bc);
        }
        if (gl < 10) {   // k = 15 tail (250 float4 per row)
            float4 v = rowp[gl + 240];
            unsigned int bt = (mrow[wb + 30] >> sh) & 0xFu;
            PROC4(v, bt);
        }

        // merge sorted-5 + reduce sq/pcount within 16-lane group
        #pragma unroll
        for (int off = 8; off >= 1; off >>= 1) {
            float b0 = __shfl_xor(t0, off, 16);
            float b1 = __shfl_xor(t1, off, 16);
            float b2 = __shfl_xor(t2, off, 16);
            float b3 = __shfl_xor(t3, off, 16);
            float b4 = __shfl_xor(t4, off, 16);
            sq     += __shfl_xor(sq, off, 16);
            pcount += __shfl_xor(pcount, off, 16);

            float m1  = fminf(t0, b0);
            float m2a = fminf(t1, b0), m2b = fminf(t0, b1);
            float m3a = fminf(t2, b0), m3b = fminf(t1, b1), m3c = fminf(t0, b2);
            float m4a = fminf(t3, b0), m4b = fminf(t2, b1), m4c = fminf(t1, b2), m4d = fminf(t0, b3);
            float c0 = fmaxf(t0, b0);
            float c1 = fmaxf(fmaxf(t1, b1), m1);
            float c2 = fmaxf(fmaxf(t2, b2), fmaxf(m2a, m2b));
            float c3 = fmaxf(fmaxf(t3, b3), fmaxf(fmaxf(m3a, m3b), m3c));
            float c4 = fmaxf(fmaxf(t4, b4), fmaxf(fmaxf(m4a, m4b), fmaxf(m4c, m4d)));
            t0 = c0; t1 = c1; t2 = c2; t3 = c3; t4 = c4;
        }

        if (gl == 0) {
            float* tp = top5 + (size_t)row * 5;
            tp[0] = t0; tp[1] = t1; tp[2] = t2; tp[3] = t3; tp[4] = t4;
            numneg[row] = NT - pcount;
            block_sq += sq;
        }
    }

    __shared__ float bsq[16];
    if (gl == 0) bsq[threadIdx.x >> 4] = block_sq;
    __syncthreads();
    if (threadIdx.x == 0) {
        float s = 0.0f;
        #pragma unroll
        for (int k = 0; k < 16; ++k) s += bsq[k];
        atomicAdd(sq_total, s);
    }

    global_barrier(barB, G2);

    // ---- Phase P: 80 pairs per block ----
    float c = 0.0f;
    unsigned int valid = 0;
    if (threadIdx.x < PAIRS_PB) {
        int p = blockIdx.x * PAIRS_PB + threadIdx.x;
        int b = pb[p];
        int t = pt[p];
        float pos = scores[(size_t)b * NT + t];
        const float* tp = top5 + (size_t)b * 5;
        #pragma unroll
        for (int k = 0; k < 5; ++k) {
            float contrib = MARGIN - (pos - tp[k]);
            c += contrib > 0.0f ? contrib : 0.0f;
        }
        int nn = numneg[b];
        valid = (unsigned int)(nn < 5 ? nn : 5);
    }
    #pragma unroll
    for (int off = 32; off >= 1; off >>= 1) {
        c     += __shfl_xor(c, off);
        valid += __shfl_xor(valid, off);
    }
    __shared__ float sc[4];
    __shared__ unsigned int sv[4];
    if ((threadIdx.x & 63) == 0) { sc[wib] = c; sv[wib] = valid; }
    __syncthreads();
    if (threadIdx.x == 0) {
        atomicAdd(rsum, sc[0] + sc[1] + sc[2] + sc[3]);
        atomicAdd(nrp,  sv[0] + sv[1] + sv[2] + sv[3]);
        __threadfence();
        unsigned int done = atomicAdd(ticket, 1u);
        if (done == G2 - 1) {
            float sqt = atomicAdd(sq_total, 0.0f);
            float rs  = atomicAdd(rsum, 0.0f);
            unsigned int n = atomicAdd(nrp, 0u);
            float loss = 0.5f * sqt / 2.0e7f;        // NB*NT = 2e7
            if (n > 0) loss += RANK_W * rs / (float)n;
            out[0] = loss;
        }
    }
}

extern "C" void kernel_launch(void* const* d_in, const int* in_sizes, int n_in,
                              void* d_out, int out_size, void* d_ws, size_t ws_size,
                              hipStream_t stream) {
    const float* scores = (const float*)d_in[0];
    const int*   pb     = (const int*)d_in[1];
    const int*   pt     = (const int*)d_in[2];
    float*       out    = (float*)d_out;

    char* ws = (char*)d_ws;
    unsigned int* mask     = (unsigned int*)ws;
    float*        sq_total = (float*)(ws + 2560000);
    float*        rsum     = (float*)(ws + 2560004);
    unsigned int* nrp      = (unsigned int*)(ws + 2560008);
    unsigned int* ticket   = (unsigned int*)(ws + 2560012);
    unsigned int* barA     = (unsigned int*)(ws + 2560016);
    unsigned int* barB     = (unsigned int*)(ws + 2560020);
    float*        top5     = (float*)(ws + 2560032);
    int*          numneg   = (int*)(ws + 2960032);

    zero_ws_kernel<<<(ZERO_U4 + 255) / 256, 256, 0, stream>>>((uint4*)ws);
    mega_kernel<<<G2, 256, 0, stream>>>(scores, pb, pt, mask, top5, numneg,
                                        sq_total, rsum, nrp, ticket, barA, barB, out);
}

// Round 9
// 169.868 us; speedup vs baseline: 1.9194x; 1.9194x over previous
//
#include <hip/hip_runtime.h>
#include <cstdint>
#include <cstddef>

#define NB 20000
#define NT 1000
#define P_PAIRS 50000
#define MARGIN 2.0f
#define RANK_W 0.3f
#define NEG_SENT -1e9f

// ---------------- workspace layout (bytes) ----------------
// [0,        2560000)  label bitmask: uint32 [NB][32]
// [2560000]  float sq_total
// [2560004]  float rsum
// [2560008]  uint  nrp
// [2560012]  uint  ticket
// zero range [0, 2560016) = 160001 uint4
// [2560016, 2960016)  float top5[NB][5]
// [2960016, 3040016)  int   numneg[NB]

#define ZERO_U4 160001

__global__ void zero_ws_kernel(uint4* __restrict__ ws) {
    int i = blockIdx.x * blockDim.x + threadIdx.x;
    if (i < ZERO_U4) ws[i] = make_uint4(0u, 0u, 0u, 0u);
}

__global__ void scatter_labels_kernel(const int* __restrict__ pb,
                                      const int* __restrict__ pt,
                                      unsigned int* __restrict__ mask) {
    int p = blockIdx.x * blockDim.x + threadIdx.x;
    if (p >= P_PAIRS) return;
    atomicOr(&mask[pb[p] * 32 + (pt[p] >> 5)], 1u << (pt[p] & 31));
}

// branchless sorted-desc insert of x into (t0>=t1>=t2>=t3>=t4)
#define INSERT5(x)                                        \
    {                                                     \
        float _x = (x);                                   \
        float n0 = fmaxf(t0, _x), s0 = fminf(t0, _x);     \
        float n1 = fmaxf(t1, s0), s1 = fminf(t1, s0);     \
        float n2 = fmaxf(t2, s1), s2 = fminf(t2, s1);     \
        float n3 = fmaxf(t3, s2), s3 = fminf(t3, s2);     \
        float n4 = fmaxf(t4, s3);                         \
        t0 = n0; t1 = n1; t2 = n2; t3 = n3; t4 = n4;      \
    }

#define PROC1(xv, lab)                                              \
    {                                                               \
        float _x = (xv);                                            \
        int _lab = (lab);                                           \
        float _s = __builtin_amdgcn_rcpf(1.0f + __expf(-_x));       \
        float _d = (float)_lab - _s;                                \
        sq = fmaf(_d, _d, sq);                                      \
        pcount += _lab;                                             \
        float _xx = _lab ? NEG_SENT : _x;                           \
        INSERT5(_xx);                                               \
    }

#define PROC4(v, bits)                        \
    PROC1((v).x, (int)(((bits) >> 0) & 1u));  \
    PROC1((v).y, (int)(((bits) >> 1) & 1u));  \
    PROC1((v).z, (int)(((bits) >> 2) & 1u));  \
    PROC1((v).w, (int)(((bits) >> 3) & 1u));

#define BATCH4(k0)                                                   \
    {                                                                \
        float4 va = rowp[gl + 16 * ((k0) + 0)];                      \
        float4 vb = rowp[gl + 16 * ((k0) + 1)];                      \
        float4 vc = rowp[gl + 16 * ((k0) + 2)];                      \
        float4 vd = rowp[gl + 16 * ((k0) + 3)];                      \
        unsigned int ba = (mrow[wb + 2 * ((k0) + 0)] >> sh) & 0xFu;  \
        unsigned int bbb = (mrow[wb + 2 * ((k0) + 1)] >> sh) & 0xFu; \
        unsigned int bc = (mrow[wb + 2 * ((k0) + 2)] >> sh) & 0xFu;  \
        unsigned int bd = (mrow[wb + 2 * ((k0) + 3)] >> sh) & 0xFu;  \
        PROC4(va, ba); PROC4(vb, bbb); PROC4(vc, bc); PROC4(vd, bd); \
    }

// Row kernel v3 + accum gate for instrumentation repeats.
// 16 lanes/row, 4 rows/wave, 16 rows/block, grid = NB/16 = 1250.
__global__ __launch_bounds__(256)
void row_kernel(const float* __restrict__ scores,
                const unsigned int* __restrict__ mask,
                float* __restrict__ sq_total,
                float* __restrict__ top5,
                int* __restrict__ numneg,
                int accum) {
    const int lane = threadIdx.x & 63;
    const int wib  = threadIdx.x >> 6;
    const int grp  = lane >> 4;
    const int gl   = lane & 15;
    const int row  = blockIdx.x * 16 + wib * 4 + grp;

    const float4* rowp = reinterpret_cast<const float4*>(scores + (size_t)row * NT);
    const unsigned int* mrow = mask + row * 32;
    const int wb = gl >> 3;
    const int sh = (gl & 7) * 4;

    float t0 = NEG_SENT, t1 = NEG_SENT, t2 = NEG_SENT, t3 = NEG_SENT, t4 = NEG_SENT;
    float sq = 0.0f;
    int pcount = 0;

    BATCH4(0);
    BATCH4(4);
    BATCH4(8);
    {   // k = 12..14 (uniform for all lanes)
        float4 va = rowp[gl + 192];
        float4 vb = rowp[gl + 208];
        float4 vc = rowp[gl + 224];
        unsigned int ba = (mrow[wb + 24] >> sh) & 0xFu;
        unsigned int bbb = (mrow[wb + 26] >> sh) & 0xFu;
        unsigned int bc = (mrow[wb + 28] >> sh) & 0xFu;
        PROC4(va, ba); PROC4(vb, bbb); PROC4(vc, bc);
    }
    if (gl < 10) {   // k = 15 tail (250 float4 per row)
        float4 v = rowp[gl + 240];
        unsigned int bt = (mrow[wb + 30] >> sh) & 0xFu;
        PROC4(v, bt);
    }

    #pragma unroll
    for (int off = 8; off >= 1; off >>= 1) {
        float b0 = __shfl_xor(t0, off, 16);
        float b1 = __shfl_xor(t1, off, 16);
        float b2 = __shfl_xor(t2, off, 16);
        float b3 = __shfl_xor(t3, off, 16);
        float b4 = __shfl_xor(t4, off, 16);
        sq     += __shfl_xor(sq, off, 16);
        pcount += __shfl_xor(pcount, off, 16);

        float m1  = fminf(t0, b0);
        float m2a = fminf(t1, b0), m2b = fminf(t0, b1);
        float m3a = fminf(t2, b0), m3b = fminf(t1, b1), m3c = fminf(t0, b2);
        float m4a = fminf(t3, b0), m4b = fminf(t2, b1), m4c = fminf(t1, b2), m4d = fminf(t0, b3);
        float c0 = fmaxf(t0, b0);
        float c1 = fmaxf(fmaxf(t1, b1), m1);
        float c2 = fmaxf(fmaxf(t2, b2), fmaxf(m2a, m2b));
        float c3 = fmaxf(fmaxf(t3, b3), fmaxf(fmaxf(m3a, m3b), m3c));
        float c4 = fmaxf(fmaxf(t4, b4), fmaxf(fmaxf(m4a, m4b), fmaxf(m4c, m4d)));
        t0 = c0; t1 = c1; t2 = c2; t3 = c3; t4 = c4;
    }

    if (gl == 0) {
        float* tp = top5 + (size_t)row * 5;
        tp[0] = t0; tp[1] = t1; tp[2] = t2; tp[3] = t3; tp[4] = t4;
        numneg[row] = NT - pcount;
    }

    __shared__ float bsq[16];
    if (gl == 0) bsq[(threadIdx.x >> 4)] = sq;
    __syncthreads();
    if (threadIdx.x == 0 && accum) {
        float s = 0.0f;
        #pragma unroll
        for (int k = 0; k < 16; ++k) s += bsq[k];
        atomicAdd(sq_total, s);
    }
}

// pair contributions + last-block finalize (ticket pattern)
__global__ __launch_bounds__(256)
void pair_finalize_kernel(const float* __restrict__ scores,
                          const int* __restrict__ pb,
                          const int* __restrict__ pt,
                          const float* __restrict__ top5,
                          const int* __restrict__ numneg,
                          float* __restrict__ sq_total,
                          float* __restrict__ rsum,
                          unsigned int* __restrict__ nrp,
                          unsigned int* __restrict__ ticket,
                          float* __restrict__ out) {
    int p = blockIdx.x * blockDim.x + threadIdx.x;
    float c = 0.0f;
    unsigned int valid = 0;
    if (p < P_PAIRS) {
        int b = pb[p];
        int t = pt[p];
        float pos = scores[(size_t)b * NT + t];
        const float* tp = top5 + (size_t)b * 5;
        #pragma unroll
        for (int k = 0; k < 5; ++k) {
            float contrib = MARGIN - (pos - tp[k]);
            c += contrib > 0.0f ? contrib : 0.0f;
        }
        int nn = numneg[b];
        valid = (unsigned int)(nn < 5 ? nn : 5);
    }
    #pragma unroll
    for (int off = 32; off >= 1; off >>= 1) {
        c     += __shfl_xor(c, off);
        valid += __shfl_xor(valid, off);
    }
    __shared__ float sc[4];
    __shared__ unsigned int sv[4];
    const int wib = threadIdx.x >> 6;
    if ((threadIdx.x & 63) == 0) { sc[wib] = c; sv[wib] = valid; }
    __syncthreads();
    if (threadIdx.x == 0) {
        atomicAdd(rsum, sc[0] + sc[1] + sc[2] + sc[3]);
        atomicAdd(nrp,  sv[0] + sv[1] + sv[2] + sv[3]);
        __threadfence();
        unsigned int done = atomicAdd(ticket, 1u);
        if (done == gridDim.x - 1) {
            float sqt = atomicAdd(sq_total, 0.0f);
            float rs  = atomicAdd(rsum, 0.0f);
            unsigned int n = atomicAdd(nrp, 0u);
            float loss = 0.5f * sqt / 2.0e7f;        // NB*NT = 2e7
            if (n > 0) loss += RANK_W * rs / (float)n;
            out[0] = loss;
        }
    }
}

extern "C" void kernel_launch(void* const* d_in, const int* in_sizes, int n_in,
                              void* d_out, int out_size, void* d_ws, size_t ws_size,
                              hipStream_t stream) {
    const float* scores = (const float*)d_in[0];
    const int*   pb     = (const int*)d_in[1];
    const int*   pt     = (const int*)d_in[2];
    float*       out    = (float*)d_out;

    char* ws = (char*)d_ws;
    unsigned int* mask     = (unsigned int*)ws;
    float*        sq_total = (float*)(ws + 2560000);
    float*        rsum     = (float*)(ws + 2560004);
    unsigned int* nrp      = (unsigned int*)(ws + 2560008);
    unsigned int* ticket   = (unsigned int*)(ws + 2560012);
    float*        top5     = (float*)(ws + 2560016);
    int*          numneg   = (int*)(ws + 2960016);

    zero_ws_kernel<<<(ZERO_U4 + 255) / 256, 256, 0, stream>>>((uint4*)ws);
    scatter_labels_kernel<<<(P_PAIRS + 255) / 256, 256, 0, stream>>>(pb, pt, mask);

    // INSTRUMENTATION: 8 identical row launches to surface row_kernel in the
    // rocprof top-5 (poison fills sit at ~46 us). Only launch 0 accumulates
    // sq_total; repeats redo idempotent top5/numneg writes. Output unchanged.
    for (int rep = 0; rep < 8; ++rep) {
        row_kernel<<<NB / 16, 256, 0, stream>>>(scores, mask, sq_total, top5,
                                                numneg, rep == 0 ? 1 : 0);
    }

    pair_finalize_kernel<<<(P_PAIRS + 255) / 256, 256, 0, stream>>>(
        scores, pb, pt, top5, numneg, sq_total, rsum, nrp, ticket, out);
}

// Round 10
// 43.801 us; speedup vs baseline: 7.4438x; 3.8782x over previous
//
#include <hip/hip_runtime.h>
#include <cstdint>
#include <cstddef>

#define NB 20000
#define NT 1000
#define P_PAIRS 50000
#define MARGIN 2.0f
#define RANK_W 0.3f
#define NEG_SENT -1e9f

#define ROWS_PB 16
#define NBLOCKS (NB / ROWS_PB)      // 1250
#define PB4 (P_PAIRS / 4)           // 12500 int4 loads of pair_bacteria
#define PLIST_CAP 512
#define MROW_W 33                   // padded mask words per row (kills LDS bank conflicts)

// ---------------- workspace layout ----------------
// [0, 20000) float4 partials[1250] = {sq_sum, rank_c, valid, 0}
// fully overwritten by K1 every call -> no zero-init needed anywhere.

// branchless sorted-desc insert of x into (t0>=t1>=t2>=t3>=t4)
#define INSERT5(x)                                        \
    {                                                     \
        float _x = (x);                                   \
        float n0 = fmaxf(t0, _x), s0 = fminf(t0, _x);     \
        float n1 = fmaxf(t1, s0), s1 = fminf(t1, s0);     \
        float n2 = fmaxf(t2, s1), s2 = fminf(t2, s1);     \
        float n3 = fmaxf(t3, s2), s3 = fminf(t3, s2);     \
        float n4 = fmaxf(t4, s3);                         \
        t0 = n0; t1 = n1; t2 = n2; t3 = n3; t4 = n4;      \
    }

#define PROC1(xv, lab)                                              \
    {                                                               \
        float _x = (xv);                                            \
        int _lab = (lab);                                           \
        float _s = __builtin_amdgcn_rcpf(1.0f + __expf(-_x));       \
        float _d = (float)_lab - _s;                                \
        sq = fmaf(_d, _d, sq);                                      \
        pcount += _lab;                                             \
        float _xx = _lab ? NEG_SENT : _x;                           \
        INSERT5(_xx);                                               \
    }

#define PROC4(v, bits)                        \
    PROC1((v).x, (int)(((bits) >> 0) & 1u));  \
    PROC1((v).y, (int)(((bits) >> 1) & 1u));  \
    PROC1((v).z, (int)(((bits) >> 2) & 1u));  \
    PROC1((v).w, (int)(((bits) >> 3) & 1u));

#define BATCH4(k0)                                                        \
    {                                                                     \
        float4 va = rowp[gl + 16 * ((k0) + 0)];                           \
        float4 vb = rowp[gl + 16 * ((k0) + 1)];                           \
        float4 vc = rowp[gl + 16 * ((k0) + 2)];                           \
        float4 vd = rowp[gl + 16 * ((k0) + 3)];                           \
        unsigned int ba = (mrow[wb + 2 * ((k0) + 0)] >> sh) & 0xFu;       \
        unsigned int bbb = (mrow[wb + 2 * ((k0) + 1)] >> sh) & 0xFu;      \
        unsigned int bc = (mrow[wb + 2 * ((k0) + 2)] >> sh) & 0xFu;       \
        unsigned int bd = (mrow[wb + 2 * ((k0) + 3)] >> sh) & 0xFu;       \
        PROC4(va, ba); PROC4(vb, bbb); PROC4(vc, bc); PROC4(vd, bd);      \
    }

// K1: per block of 16 rows: LDS mask build from pair scan -> row pass
// (sq, top5, numneg, all LDS-local) -> local pair contributions -> 1 float4.
__global__ __launch_bounds__(256)
void fused_row_pair_kernel(const float* __restrict__ scores,
                           const int* __restrict__ pb,
                           const int* __restrict__ pt,
                           float4* __restrict__ partials) {
    const int tid  = threadIdx.x;
    const int lane = tid & 63;
    const int wib  = tid >> 6;          // wave in block 0..3
    const int grp  = lane >> 4;         // group in wave  0..3
    const int gl   = lane & 15;         // lane in group  0..15
    const int rowBase = blockIdx.x * ROWS_PB;

    __shared__ unsigned int smask[ROWS_PB * MROW_W];   // 528 words, padded stride
    __shared__ float  stop5[ROWS_PB][5];
    __shared__ int    snn[ROWS_PB];
    __shared__ int    plist[PLIST_CAP];                // packed (localRow<<10)|t
    __shared__ int    pcnt;
    __shared__ float  bsq[ROWS_PB];
    __shared__ float  sc[4];
    __shared__ unsigned int sv[4];

    // ---- Phase 1: zero LDS mask + counter ----
    for (int i = tid; i < ROWS_PB * MROW_W; i += 256) smask[i] = 0u;
    if (tid == 0) pcnt = 0;
    __syncthreads();

    // ---- Phase 2: scan all pairs; keep those in [rowBase, rowBase+16) ----
    const int4* pb4 = reinterpret_cast<const int4*>(pb);
    for (int i = tid; i < PB4; i += 256) {
        int4 v = pb4[i];
        int bs[4] = {v.x, v.y, v.z, v.w};
        #pragma unroll
        for (int j = 0; j < 4; ++j) {
            unsigned int d = (unsigned int)(bs[j] - rowBase);
            if (d < ROWS_PB) {
                int t = pt[i * 4 + j];
                atomicOr(&smask[d * MROW_W + (t >> 5)], 1u << (t & 31));
                int idx = atomicAdd(&pcnt, 1);
                if (idx < PLIST_CAP) plist[idx] = ((int)d << 10) | t;
            }
        }
    }
    __syncthreads();

    // ---- Phase 3: row pass (identical math to R7, mask from LDS) ----
    const int localRow = wib * 4 + grp;
    const int row = rowBase + localRow;
    const float4* rowp = reinterpret_cast<const float4*>(scores + (size_t)row * NT);
    const unsigned int* mrow = smask + localRow * MROW_W;
    const int wb = gl >> 3;
    const int sh = (gl & 7) * 4;

    float t0 = NEG_SENT, t1 = NEG_SENT, t2 = NEG_SENT, t3 = NEG_SENT, t4 = NEG_SENT;
    float sq = 0.0f;
    int pcount = 0;

    BATCH4(0);
    BATCH4(4);
    BATCH4(8);
    {   // k = 12..14
        float4 va = rowp[gl + 192];
        float4 vb = rowp[gl + 208];
        float4 vc = rowp[gl + 224];
        unsigned int ba = (mrow[wb + 24] >> sh) & 0xFu;
        unsigned int bbb = (mrow[wb + 26] >> sh) & 0xFu;
        unsigned int bc = (mrow[wb + 28] >> sh) & 0xFu;
        PROC4(va, ba); PROC4(vb, bbb); PROC4(vc, bc);
    }
    if (gl < 10) {   // k = 15 tail (250 float4 per row)
        float4 v = rowp[gl + 240];
        unsigned int bt = (mrow[wb + 30] >> sh) & 0xFu;
        PROC4(v, bt);
    }

    #pragma unroll
    for (int off = 8; off >= 1; off >>= 1) {
        float b0 = __shfl_xor(t0, off, 16);
        float b1 = __shfl_xor(t1, off, 16);
        float b2 = __shfl_xor(t2, off, 16);
        float b3 = __shfl_xor(t3, off, 16);
        float b4 = __shfl_xor(t4, off, 16);
        sq     += __shfl_xor(sq, off, 16);
        pcount += __shfl_xor(pcount, off, 16);

        float m1  = fminf(t0, b0);
        float m2a = fminf(t1, b0), m2b = fminf(t0, b1);
        float m3a = fminf(t2, b0), m3b = fminf(t1, b1), m3c = fminf(t0, b2);
        float m4a = fminf(t3, b0), m4b = fminf(t2, b1), m4c = fminf(t1, b2), m4d = fminf(t0, b3);
        float c0 = fmaxf(t0, b0);
        float c1 = fmaxf(fmaxf(t1, b1), m1);
        float c2 = fmaxf(fmaxf(t2, b2), fmaxf(m2a, m2b));
        float c3 = fmaxf(fmaxf(t3, b3), fmaxf(fmaxf(m3a, m3b), m3c));
        float c4 = fmaxf(fmaxf(t4, b4), fmaxf(fmaxf(m4a, m4b), fmaxf(m4c, m4d)));
        t0 = c0; t1 = c1; t2 = c2; t3 = c3; t4 = c4;
    }

    if (gl == 0) {
        stop5[localRow][0] = t0; stop5[localRow][1] = t1; stop5[localRow][2] = t2;
        stop5[localRow][3] = t3; stop5[localRow][4] = t4;
        snn[localRow] = NT - pcount;
        bsq[localRow] = sq;
    }
    __syncthreads();

    // ---- Phase 4: this block's pair contributions (all data local) ----
    float c = 0.0f;
    unsigned int valid = 0;
    int np = pcnt;
    if (np <= PLIST_CAP) {
        for (int k = tid; k < np; k += 256) {
            int e = plist[k];
            int lr = e >> 10, t = e & 1023;
            float pos = scores[(size_t)(rowBase + lr) * NT + t];
            #pragma unroll
            for (int q = 0; q < 5; ++q) {
                float contrib = MARGIN - (pos - stop5[lr][q]);
                c += contrib > 0.0f ? contrib : 0.0f;
            }
            int nn = snn[lr];
            valid += (unsigned int)(nn < 5 ? nn : 5);
        }
    } else {
        // overflow fallback: rescan pair list (never taken for this dataset)
        for (int i = tid; i < PB4; i += 256) {
            int4 v = pb4[i];
            int bs[4] = {v.x, v.y, v.z, v.w};
            #pragma unroll
            for (int j = 0; j < 4; ++j) {
                unsigned int d = (unsigned int)(bs[j] - rowBase);
                if (d < ROWS_PB) {
                    int t = pt[i * 4 + j];
                    float pos = scores[(size_t)(rowBase + d) * NT + t];
                    #pragma unroll
                    for (int q = 0; q < 5; ++q) {
                        float contrib = MARGIN - (pos - stop5[d][q]);
                        c += contrib > 0.0f ? contrib : 0.0f;
                    }
                    int nn = snn[d];
                    valid += (unsigned int)(nn < 5 ? nn : 5);
                }
            }
        }
    }

    #pragma unroll
    for (int off = 32; off >= 1; off >>= 1) {
        c     += __shfl_xor(c, off);
        valid += __shfl_xor(valid, off);
    }
    if ((tid & 63) == 0) { sc[wib] = c; sv[wib] = valid; }
    __syncthreads();
    if (tid == 0) {
        float s = 0.0f;
        #pragma unroll
        for (int k = 0; k < ROWS_PB; ++k) s += bsq[k];
        float cb = sc[0] + sc[1] + sc[2] + sc[3];
        float vb = (float)(sv[0] + sv[1] + sv[2] + sv[3]);
        partials[blockIdx.x] = make_float4(s, cb, vb, 0.0f);
    }
}

// K2: single-block reduction of 1250 partials -> loss
__global__ __launch_bounds__(256)
void finalize_kernel(const float4* __restrict__ partials,
                     float* __restrict__ out) {
    float s = 0.0f, cb = 0.0f, vb = 0.0f;
    for (int i = threadIdx.x; i < NBLOCKS; i += 256) {
        float4 p = partials[i];
        s += p.x; cb += p.y; vb += p.z;
    }
    #pragma unroll
    for (int off = 32; off >= 1; off >>= 1) {
        s  += __shfl_xor(s, off);
        cb += __shfl_xor(cb, off);
        vb += __shfl_xor(vb, off);
    }
    __shared__ float ss[4], scc[4], svv[4];
    int wib = threadIdx.x >> 6;
    if ((threadIdx.x & 63) == 0) { ss[wib] = s; scc[wib] = cb; svv[wib] = vb; }
    __syncthreads();
    if (threadIdx.x == 0) {
        float st = ss[0] + ss[1] + ss[2] + ss[3];
        float ct = scc[0] + scc[1] + scc[2] + scc[3];
        float vt = svv[0] + svv[1] + svv[2] + svv[3];
        float loss = 0.5f * st / 2.0e7f;            // NB*NT = 2e7
        if (vt > 0.0f) loss += RANK_W * ct / vt;
        out[0] = loss;
    }
}

extern "C" void kernel_launch(void* const* d_in, const int* in_sizes, int n_in,
                              void* d_out, int out_size, void* d_ws, size_t ws_size,
                              hipStream_t stream) {
    const float* scores = (const float*)d_in[0];
    const int*   pb     = (const int*)d_in[1];
    const int*   pt     = (const int*)d_in[2];
    float*       out    = (float*)d_out;
    float4*      partials = (float4*)d_ws;

    fused_row_pair_kernel<<<NBLOCKS, 256, 0, stream>>>(scores, pb, pt, partials);
    finalize_kernel<<<1, 256, 0, stream>>>(partials, out);
}